// Round 1
// baseline (2469.610 us; speedup 1.0000x reference)
//
#include <hip/hip_runtime.h>
#include <hip/hip_bf16.h>
#include <cstdint>

// ---------------------------------------------------------------------------
// Problem constants
#define IMGSZ 224
#define OUTSZ 112          // IMG/STRIDE
#define POOLSZ 56
#define OCN 128
#define BN_ 32
#define PIX1 (OUTSZ*OUTSZ)     // 12544
#define PIX2 (POOLSZ*POOLSZ)   // 3136
#define K1LEN 147              // 3*7*7
#define K2LEN 1152             // 128*3*3

// ---------------------------------------------------------------------------
// Map kernel: per output pixel of stage-1, compute (src_y, src_x) = top-left of
// the 7x7 stride-2 window in PADDED (pad=3) input coordinates.
// Replicates numpy: iwp = trunc(float32(iw+6)/float32(scale)); ti,li -=3; bi,ri +=3
__global__ __launch_bounds__(256) void k_map(int2* __restrict__ map) {
    int p = blockIdx.x * 256 + threadIdx.x;   // 49*256 = 12544 exact
    int oy = p / OUTSZ, ox = p % OUTSZ;
    int e = min(min(oy, ox), min(111 - oy, 111 - ox));
    int s = e >> 3;                            // ring 0..6
    int a = 16 * s, b = a + 16, c = 224 - b, d = 224 - a;
    int ao = a >> 1, bo = b >> 1, co = c >> 1, dd = d >> 1;
    int ti, li, bi, ri;
    if      (oy >= ao && oy < bo && ox >= ao && ox < co) { ti=a; li=a; bi=b; ri=c; } // top
    else if (oy >= bo && oy < dd && ox >= ao && ox < bo) { ti=b; li=a; bi=d; ri=b; } // left
    else if (oy >= co && oy < dd && ox >= bo && ox < dd) { ti=c; li=b; bi=d; ri=d; } // bottom
    else                                                 { ti=a; li=c; bi=c; ri=d; } // right
    // scale = float32(linspace(2,1,7)[s]) ; numpy computes in f64 then casts
    float scale = (float)(2.0 - (double)s * 0.16666666666666666);
    int tip = (int)((float)(ti + 6) / scale) - 3;
    int lip = (int)((float)(li + 6) / scale) - 3;
    int bip = (int)((float)(bi + 6) / scale) + 3;
    int rip = (int)((float)(ri + 6) / scale) + 3;
    int fh = (bip - tip - 7) / 2 + 1;          // conv VALID stride2 k7 output dims
    int fw = (rip - lip - 7) / 2 + 1;
    int to = ti >> 1, lo = li >> 1, bo2 = bi >> 1, ro = ri >> 1;
    int i = oy - to, j = ox - lo;
    int pp = (i * fh) / (bo2 - to);            // nearest-neighbor upsample index
    int qq = (j * fw) / (ro - lo);
    map[p] = make_int2(tip + 2 * pp, lip + 2 * qq);
}

// ---------------------------------------------------------------------------
// Stage-1 gather conv: out1[n][oc][p] = sum_{ic,ky,kx} inp[n][ic][sy+ky-3][sx+kx-3] * w[oc][ic][ky][kx]
// Each thread: 1 pixel x 8 output channels. Weights are block-uniform (scalar loads).
__global__ __launch_bounds__(256) void k_conv1(const float* __restrict__ inp,
                                               const float* __restrict__ w,
                                               const int2* __restrict__ map,
                                               float* __restrict__ out1) {
    int p   = blockIdx.x * 256 + threadIdx.x;  // 0..12543 exact
    int oc0 = blockIdx.y * 8;
    int n   = blockIdx.z;
    int2 m = map[p];
    int sy = m.x, sx = m.y;
    const float* wp = w + (size_t)oc0 * K1LEN;
    float acc[8] = {0.f,0.f,0.f,0.f,0.f,0.f,0.f,0.f};
    for (int ic = 0; ic < 3; ic++) {
        const float* ibase = inp + ((size_t)(n * 3 + ic)) * (IMGSZ * IMGSZ);
        for (int ky = 0; ky < 7; ky++) {
            int y = sy + ky - 3;
            bool yok = ((unsigned)y < (unsigned)IMGSZ);
            const float* row = ibase + y * IMGSZ;
            int kbase = (ic * 7 + ky) * 7;
            #pragma unroll
            for (int kx = 0; kx < 7; kx++) {
                int x = sx + kx - 3;
                float v = (yok && (unsigned)x < (unsigned)IMGSZ) ? row[x] : 0.f;
                #pragma unroll
                for (int j = 0; j < 8; j++)
                    acc[j] = fmaf(v, wp[j * K1LEN + kbase + kx], acc[j]);
            }
        }
    }
    size_t ob = ((size_t)(n * OCN + oc0)) * PIX1 + p;
    #pragma unroll
    for (int j = 0; j < 8; j++) out1[ob + (size_t)j * PIX1] = acc[j];
}

// ---------------------------------------------------------------------------
// Per-channel sum / sumsq over one (n,c) plane per block.
__global__ __launch_bounds__(256) void k_stats(const float* __restrict__ x, int planeHW,
                                               float* __restrict__ sum, float* __restrict__ sumsq) {
    int n = blockIdx.x, c = blockIdx.y;
    const float* pl = x + ((size_t)(n * OCN + c)) * planeHW;
    float s = 0.f, s2 = 0.f;
    for (int i = threadIdx.x; i < planeHW; i += 256) {
        float v = pl[i];
        s += v; s2 += v * v;
    }
    #pragma unroll
    for (int off = 32; off > 0; off >>= 1) {
        s  += __shfl_down(s, off, 64);
        s2 += __shfl_down(s2, off, 64);
    }
    __shared__ float ls[4], ls2[4];
    int wid = threadIdx.x >> 6, lid = threadIdx.x & 63;
    if (lid == 0) { ls[wid] = s; ls2[wid] = s2; }
    __syncthreads();
    if (threadIdx.x == 0) {
        float t = ls[0] + ls[1] + ls[2] + ls[3];
        float t2 = ls2[0] + ls2[1] + ls2[2] + ls2[3];
        atomicAdd(&sum[c], t);
        atomicAdd(&sumsq[c], t2);
    }
}

// scale[c] = gamma*rsqrt(var+eps); shift[c] = beta - mean*scale
__global__ void k_fin(const float* __restrict__ sum, const float* __restrict__ sumsq,
                      const float* __restrict__ gamma, const float* __restrict__ beta,
                      float invN, float* __restrict__ scale, float* __restrict__ shift) {
    int c = threadIdx.x;
    if (c >= OCN) return;
    float m = sum[c] * invN;
    float v = sumsq[c] * invN - m * m;
    float sc = gamma[c] * rsqrtf(v + 1e-5f);
    scale[c] = sc;
    shift[c] = beta[c] - m * sc;
}

// ---------------------------------------------------------------------------
// Fused BN1 affine + ReLU + 3x3 stride-2 pad-1 maxpool: out1(112x112) -> h(56x56)
__global__ __launch_bounds__(256) void k_bnpool(const float* __restrict__ out1,
                                                const float* __restrict__ scale,
                                                const float* __restrict__ shift,
                                                float* __restrict__ h) {
    int idx = blockIdx.x * 256 + threadIdx.x;
    if (idx >= PIX2) return;
    int c = blockIdx.y, n = blockIdx.z;
    int py = idx / POOLSZ, px = idx % POOLSZ;
    const float* base = out1 + ((size_t)(n * OCN + c)) * PIX1;
    float sc = scale[c], sh = shift[c];
    float mmax = -1e30f;
    #pragma unroll
    for (int dy = 0; dy < 3; dy++) {
        int y = 2 * py - 1 + dy;
        if ((unsigned)y >= (unsigned)OUTSZ) continue;
        #pragma unroll
        for (int dx = 0; dx < 3; dx++) {
            int x = 2 * px - 1 + dx;
            if ((unsigned)x >= (unsigned)OUTSZ) continue;
            mmax = fmaxf(mmax, fmaf(sc, base[y * OUTSZ + x], sh));
        }
    }
    h[((size_t)(n * OCN + c)) * PIX2 + idx] = fmaxf(mmax, 0.f);
}

// ---------------------------------------------------------------------------
// conv2: 3x3 pad 1 stride 1, 128->128 channels on h (32,128,56,56) -> out (pre-BN2)
// Each thread: 1 pixel x 8 oc; weights block-uniform (scalar loads).
__global__ __launch_bounds__(256) void k_conv2(const float* __restrict__ h,
                                               const float* __restrict__ w2,
                                               float* __restrict__ out) {
    int idx = blockIdx.x * 256 + threadIdx.x;
    if (idx >= PIX2) return;
    int oc0 = blockIdx.y * 8, n = blockIdx.z;
    int py = idx / POOLSZ, px = idx % POOLSZ;
    const float* wp = w2 + (size_t)oc0 * K2LEN;
    const float* hb = h + (size_t)n * OCN * PIX2;
    float acc[8] = {0.f,0.f,0.f,0.f,0.f,0.f,0.f,0.f};
    for (int ic = 0; ic < OCN; ic++) {
        const float* plane = hb + (size_t)ic * PIX2;
        int kb = ic * 9;
        #pragma unroll
        for (int dy = 0; dy < 3; dy++) {
            int y = py - 1 + dy;
            bool yok = ((unsigned)y < (unsigned)POOLSZ);
            const float* row = plane + y * POOLSZ;
            #pragma unroll
            for (int dx = 0; dx < 3; dx++) {
                int x = px - 1 + dx;
                float v = (yok && (unsigned)x < (unsigned)POOLSZ) ? row[x] : 0.f;
                #pragma unroll
                for (int j = 0; j < 8; j++)
                    acc[j] = fmaf(v, wp[j * K2LEN + kb + dy * 3 + dx], acc[j]);
            }
        }
    }
    size_t ob = ((size_t)(n * OCN + oc0)) * PIX2 + idx;
    #pragma unroll
    for (int j = 0; j < 8; j++) out[ob + (size_t)j * PIX2] = acc[j];
}

// BN2 affine + ReLU, in-place on d_out. 12,845,056 = 50176*256 exact.
__global__ __launch_bounds__(256) void k_bnrelu(float* __restrict__ y,
                                                const float* __restrict__ scale,
                                                const float* __restrict__ shift) {
    size_t i = (size_t)blockIdx.x * 256 + threadIdx.x;
    int c = (int)((i / PIX2) & (OCN - 1));
    float v = fmaf(scale[c], y[i], shift[c]);
    y[i] = fmaxf(v, 0.f);
}

// ---------------------------------------------------------------------------
extern "C" void kernel_launch(void* const* d_in, const int* in_sizes, int n_in,
                              void* d_out, int out_size, void* d_ws, size_t ws_size,
                              hipStream_t stream) {
    const float* inp = (const float*)d_in[0];
    const float* w1  = (const float*)d_in[1];
    const float* g1  = (const float*)d_in[2];
    const float* b1  = (const float*)d_in[3];
    const float* w2  = (const float*)d_in[4];
    const float* g2  = (const float*)d_in[5];
    const float* b2  = (const float*)d_in[6];
    float* out = (float*)d_out;

    char* ws = (char*)d_ws;
    int2*  map   = (int2*)ws;                              // 100,352 B
    float* stats = (float*)(ws + 128 * 1024);              // 8*128 floats
    float* out1  = (float*)(ws + 256 * 1024);              // 32*128*12544*4 = 205,520,896 B
    float* hbuf  = (float*)(ws + 256 * 1024 + 205520896ULL); // 51,380,224 B

    float* sum1 = stats + 0,   *sq1 = stats + 128, *sc1 = stats + 256, *sh1 = stats + 384;
    float* sum2 = stats + 512, *sq2 = stats + 640, *sc2 = stats + 768, *sh2 = stats + 896;

    hipMemsetAsync(stats, 0, 1024 * sizeof(float), stream);

    k_map<<<dim3(49), 256, 0, stream>>>(map);
    k_conv1<<<dim3(49, OCN / 8, BN_), 256, 0, stream>>>(inp, w1, map, out1);
    k_stats<<<dim3(BN_, OCN), 256, 0, stream>>>(out1, PIX1, sum1, sq1);
    k_fin<<<1, 128, 0, stream>>>(sum1, sq1, g1, b1, 1.f / (BN_ * PIX1), sc1, sh1);
    k_bnpool<<<dim3((PIX2 + 255) / 256, OCN, BN_), 256, 0, stream>>>(out1, sc1, sh1, hbuf);
    k_conv2<<<dim3((PIX2 + 255) / 256, OCN / 8, BN_), 256, 0, stream>>>(hbuf, w2, out);
    k_stats<<<dim3(BN_, OCN), 256, 0, stream>>>(out, PIX2, sum2, sq2);
    k_fin<<<1, 128, 0, stream>>>(sum2, sq2, g2, b2, 1.f / (BN_ * PIX2), sc2, sh2);
    k_bnrelu<<<dim3(50176), 256, 0, stream>>>(out, sc2, sh2);
}

// Round 2
// 1409.463 us; speedup vs baseline: 1.7522x; 1.7522x over previous
//
#include <hip/hip_runtime.h>
#include <hip/hip_bf16.h>
#include <cstdint>

// ---------------------------------------------------------------------------
#define IMGSZ 224
#define OUTSZ 112
#define POOLSZ 56
#define OCN 128
#define BN_ 32
#define PIX1 (OUTSZ*OUTSZ)     // 12544
#define PIX2 (POOLSZ*POOLSZ)   // 3136
#define K1LEN 147
#define HP 58                  // padded pooled dim (56 + 2)
#define HSTRIDE (HP*HP*OCN)    // 430592 elems per n in h2p

typedef float f32x4 __attribute__((ext_vector_type(4)));
typedef short bf16x8 __attribute__((ext_vector_type(8)));

// ---------------------------------------------------------------------------
// Map kernel (unchanged): per stage-1 output pixel -> 7x7 window origin.
__global__ __launch_bounds__(256) void k_map(int2* __restrict__ map) {
    int p = blockIdx.x * 256 + threadIdx.x;
    int oy = p / OUTSZ, ox = p % OUTSZ;
    int e = min(min(oy, ox), min(111 - oy, 111 - ox));
    int s = e >> 3;
    int a = 16 * s, b = a + 16, c = 224 - b, d = 224 - a;
    int ao = a >> 1, bo = b >> 1, co = c >> 1, dd = d >> 1;
    int ti, li, bi, ri;
    if      (oy >= ao && oy < bo && ox >= ao && ox < co) { ti=a; li=a; bi=b; ri=c; }
    else if (oy >= bo && oy < dd && ox >= ao && ox < bo) { ti=b; li=a; bi=d; ri=b; }
    else if (oy >= co && oy < dd && ox >= bo && ox < dd) { ti=c; li=b; bi=d; ri=d; }
    else                                                 { ti=a; li=c; bi=c; ri=d; }
    float scale = (float)(2.0 - (double)s * 0.16666666666666666);
    int tip = (int)((float)(ti + 6) / scale) - 3;
    int lip = (int)((float)(li + 6) / scale) - 3;
    int bip = (int)((float)(bi + 6) / scale) + 3;
    int rip = (int)((float)(ri + 6) / scale) + 3;
    int fh = (bip - tip - 7) / 2 + 1;
    int fw = (rip - lip - 7) / 2 + 1;
    int to = ti >> 1, lo = li >> 1, bo2 = bi >> 1, ro = ri >> 1;
    int i = oy - to, j = ox - lo;
    int pp = (i * fh) / (bo2 - to);
    int qq = (j * fw) / (ro - lo);
    map[p] = make_int2(tip + 2 * pp, lip + 2 * qq);
}

// ---------------------------------------------------------------------------
// Stage-1 gather conv -> out1 in NHWC fp32: out1[n][p][oc]
__global__ __launch_bounds__(256) void k_conv1(const float* __restrict__ inp,
                                               const float* __restrict__ w,
                                               const int2* __restrict__ map,
                                               float* __restrict__ out1) {
    int p   = blockIdx.x * 256 + threadIdx.x;
    int oc0 = blockIdx.y * 8;
    int n   = blockIdx.z;
    int2 m = map[p];
    int sy = m.x, sx = m.y;
    const float* wp = w + (size_t)oc0 * K1LEN;
    float acc[8] = {0.f,0.f,0.f,0.f,0.f,0.f,0.f,0.f};
    for (int ic = 0; ic < 3; ic++) {
        const float* ibase = inp + ((size_t)(n * 3 + ic)) * (IMGSZ * IMGSZ);
        for (int ky = 0; ky < 7; ky++) {
            int y = sy + ky - 3;
            bool yok = ((unsigned)y < (unsigned)IMGSZ);
            const float* row = ibase + y * IMGSZ;
            int kbase = (ic * 7 + ky) * 7;
            #pragma unroll
            for (int kx = 0; kx < 7; kx++) {
                int x = sx + kx - 3;
                float v = (yok && (unsigned)x < (unsigned)IMGSZ) ? row[x] : 0.f;
                #pragma unroll
                for (int j = 0; j < 8; j++)
                    acc[j] = fmaf(v, wp[j * K1LEN + kbase + kx], acc[j]);
            }
        }
    }
    float* ob = out1 + ((size_t)n * PIX1 + p) * OCN + oc0;
    #pragma unroll
    for (int j = 0; j < 8; j++) ob[j] = acc[j];
}

// ---------------------------------------------------------------------------
// NHWC per-channel sum/sumsq. Block covers 512 consecutive pixels (all c).
__global__ __launch_bounds__(256) void k_statsN(const float* __restrict__ x,
                                                float* __restrict__ sum, float* __restrict__ sumsq) {
    int tid = threadIdx.x;
    int c = tid & 127, po = tid >> 7;
    size_t base = (size_t)blockIdx.x * 512;
    float s = 0.f, s2 = 0.f;
    for (int i = 0; i < 256; i++) {
        float v = x[(base + 2 * i + po) * OCN + c];
        s += v; s2 += v * v;
    }
    __shared__ float ss[256], ss2[256];
    ss[tid] = s; ss2[tid] = s2;
    __syncthreads();
    if (tid < 128) {
        atomicAdd(&sum[tid], ss[tid] + ss[tid + 128]);
        atomicAdd(&sumsq[tid], ss2[tid] + ss2[tid + 128]);
    }
}

// NCHW per-channel stats (for BN2 on d_out) — one (n,c) plane per block.
__global__ __launch_bounds__(256) void k_stats(const float* __restrict__ x, int planeHW,
                                               float* __restrict__ sum, float* __restrict__ sumsq) {
    int n = blockIdx.x, c = blockIdx.y;
    const float* pl = x + ((size_t)(n * OCN + c)) * planeHW;
    float s = 0.f, s2 = 0.f;
    for (int i = threadIdx.x; i < planeHW; i += 256) {
        float v = pl[i];
        s += v; s2 += v * v;
    }
    #pragma unroll
    for (int off = 32; off > 0; off >>= 1) {
        s  += __shfl_down(s, off, 64);
        s2 += __shfl_down(s2, off, 64);
    }
    __shared__ float ls[4], ls2[4];
    int wid = threadIdx.x >> 6, lid = threadIdx.x & 63;
    if (lid == 0) { ls[wid] = s; ls2[wid] = s2; }
    __syncthreads();
    if (threadIdx.x == 0) {
        atomicAdd(&sum[c],   ls[0] + ls[1] + ls[2] + ls[3]);
        atomicAdd(&sumsq[c], ls2[0] + ls2[1] + ls2[2] + ls2[3]);
    }
}

__global__ void k_fin(const float* __restrict__ sum, const float* __restrict__ sumsq,
                      const float* __restrict__ gamma, const float* __restrict__ beta,
                      float invN, float* __restrict__ scale, float* __restrict__ shift) {
    int c = threadIdx.x;
    if (c >= OCN) return;
    float m = sum[c] * invN;
    float v = sumsq[c] * invN - m * m;
    float sc = gamma[c] * rsqrtf(v + 1e-5f);
    scale[c] = sc;
    shift[c] = beta[c] - m * sc;
}

// ---------------------------------------------------------------------------
// BN1 affine + 3x3/2 maxpool + ReLU: NHWC fp32 (112x112) -> padded NHWC bf16 (58x58)
// Thread: c = tid&127, one pooled pixel per 128-thread group.
__global__ __launch_bounds__(256) void k_bnpool(const float* __restrict__ out1,
                                                const float* __restrict__ scale,
                                                const float* __restrict__ shift,
                                                short* __restrict__ h2p) {
    int tid = threadIdx.x;
    int c = tid & 127;
    int pp = blockIdx.x * 2 + (tid >> 7);
    int n = blockIdx.y;
    int py = pp / POOLSZ, px = pp % POOLSZ;
    const float* base = out1 + (size_t)n * PIX1 * OCN;
    float sc = scale[c], sh = shift[c];
    float mmax = -1e30f;
    #pragma unroll
    for (int dy = 0; dy < 3; dy++) {
        int y = 2 * py - 1 + dy;
        if ((unsigned)y >= (unsigned)OUTSZ) continue;
        #pragma unroll
        for (int dx = 0; dx < 3; dx++) {
            int x = 2 * px - 1 + dx;
            if ((unsigned)x >= (unsigned)OUTSZ) continue;
            mmax = fmaxf(mmax, fmaf(sc, base[((size_t)y * OUTSZ + x) * OCN + c], sh));
        }
    }
    mmax = fmaxf(mmax, 0.f);
    __hip_bfloat16 b = __float2bfloat16(mmax);
    h2p[(size_t)n * HSTRIDE + ((py + 1) * HP + (px + 1)) * OCN + c] = *(short*)&b;
}

// ---------------------------------------------------------------------------
// Weight repack: w2 OIHW fp32 -> w2b [shift][oc][ic] bf16
__global__ __launch_bounds__(256) void k_wconv(const float* __restrict__ w2,
                                               short* __restrict__ w2b) {
    int idx = blockIdx.x * 256 + threadIdx.x;   // 576*256 = 147456 exact
    int s = idx % 9;
    int t = idx / 9;
    int ic = t & 127;
    int oc = t >> 7;
    __hip_bfloat16 b = __float2bfloat16(w2[idx]);
    w2b[(s * OCN + oc) * OCN + ic] = *(short*)&b;
}

// ---------------------------------------------------------------------------
// conv2 via bf16 MFMA: 9 shifted K=128 GEMMs. Block = 4 waves; wave = 128 oc x 32 px.
// A (weights) and B (h2p NHWC) fragments loaded straight from global (L2-resident).
__global__ __launch_bounds__(256) void k_conv2m(const short* __restrict__ h2p,
                                                const short* __restrict__ w2b,
                                                float* __restrict__ out) {
    int tid = threadIdx.x;
    int wave = tid >> 6, lane = tid & 63;
    int q = lane >> 4, l16 = lane & 15;
    int n = blockIdx.y;
    int px0 = blockIdx.x * 128 + wave * 32 + l16;
    int px1 = px0 + 16;
    bool st0 = px0 < PIX2, st1 = px1 < PIX2;
    int p0 = st0 ? px0 : (PIX2 - 1);
    int p1 = st1 ? px1 : (PIX2 - 1);
    int y0 = p0 / POOLSZ, x0 = p0 % POOLSZ;
    int y1 = p1 / POOLSZ, x1 = p1 % POOLSZ;
    const short* hb = h2p + (size_t)n * HSTRIDE;
    int b0 = (y0 * HP + x0) * OCN;   // top-left of 3x3 in padded coords
    int b1 = (y1 * HP + x1) * OCN;

    f32x4 acc[8][2];
    #pragma unroll
    for (int t = 0; t < 8; t++) { acc[t][0] = (f32x4){0,0,0,0}; acc[t][1] = (f32x4){0,0,0,0}; }

    for (int icc = 0; icc < 4; icc++) {
        int kof = icc * 32 + q * 8;
        #pragma unroll
        for (int s = 0; s < 9; s++) {
            int off = ((s / 3) * HP + (s % 3)) * OCN + kof;
            bf16x8 bf0 = *(const bf16x8*)(hb + b0 + off);
            bf16x8 bf1 = *(const bf16x8*)(hb + b1 + off);
            const short* wbase = w2b + (s * OCN + l16) * OCN + kof;
            #pragma unroll
            for (int t = 0; t < 8; t++) {
                bf16x8 af = *(const bf16x8*)(wbase + t * 16 * OCN);
                acc[t][0] = __builtin_amdgcn_mfma_f32_16x16x32_bf16(af, bf0, acc[t][0], 0, 0, 0);
                acc[t][1] = __builtin_amdgcn_mfma_f32_16x16x32_bf16(af, bf1, acc[t][1], 0, 0, 0);
            }
        }
    }
    // C/D layout: col(px)=lane&15, row(oc)=quad*4+reg
    float* on = out + (size_t)n * OCN * PIX2;
    #pragma unroll
    for (int t = 0; t < 8; t++) {
        int ocb = t * 16 + q * 4;
        #pragma unroll
        for (int r = 0; r < 4; r++) {
            if (st0) on[(size_t)(ocb + r) * PIX2 + px0] = acc[t][0][r];
            if (st1) on[(size_t)(ocb + r) * PIX2 + px1] = acc[t][1][r];
        }
    }
}

// BN2 affine + ReLU in-place on d_out (NCHW).
__global__ __launch_bounds__(256) void k_bnrelu(float* __restrict__ y,
                                                const float* __restrict__ scale,
                                                const float* __restrict__ shift) {
    size_t i = (size_t)blockIdx.x * 256 + threadIdx.x;
    int c = (int)((i / PIX2) & (OCN - 1));
    float v = fmaf(scale[c], y[i], shift[c]);
    y[i] = fmaxf(v, 0.f);
}

// ---------------------------------------------------------------------------
extern "C" void kernel_launch(void* const* d_in, const int* in_sizes, int n_in,
                              void* d_out, int out_size, void* d_ws, size_t ws_size,
                              hipStream_t stream) {
    const float* inp = (const float*)d_in[0];
    const float* w1  = (const float*)d_in[1];
    const float* g1  = (const float*)d_in[2];
    const float* b1  = (const float*)d_in[3];
    const float* w2  = (const float*)d_in[4];
    const float* g2  = (const float*)d_in[5];
    const float* b2  = (const float*)d_in[6];
    float* out = (float*)d_out;

    char* ws = (char*)d_ws;
    int2*  map   = (int2*)ws;                         // 100,352 B
    float* stats = (float*)(ws + 102400);             // 4 KB
    short* w2b   = (short*)(ws + 106496);             // 294,912 B
    short* h2p   = (short*)(ws + 401408);             // 27,557,888 B
    float* out1  = (float*)(ws + 27959296ULL);        // 205,520,896 B

    float* sum1 = stats + 0,   *sq1 = stats + 128, *sc1 = stats + 256, *sh1 = stats + 384;
    float* sum2 = stats + 512, *sq2 = stats + 640, *sc2 = stats + 768, *sh2 = stats + 896;

    hipMemsetAsync(stats, 0, 1024 * sizeof(float), stream);
    hipMemsetAsync(h2p, 0, 27557888ULL, stream);      // zero padding for shifts

    k_map  <<<dim3(49), 256, 0, stream>>>(map);
    k_wconv<<<dim3(576), 256, 0, stream>>>(w2, w2b);
    k_conv1<<<dim3(49, OCN / 8, BN_), 256, 0, stream>>>(inp, w1, map, out1);
    k_statsN<<<dim3(784), 256, 0, stream>>>(out1, sum1, sq1);
    k_fin  <<<1, 128, 0, stream>>>(sum1, sq1, g1, b1, 1.f / (BN_ * PIX1), sc1, sh1);
    k_bnpool<<<dim3(PIX2 / 2, BN_), 256, 0, stream>>>(out1, sc1, sh1, h2p);
    k_conv2m<<<dim3(25, BN_), 256, 0, stream>>>(h2p, w2b, out);
    k_stats<<<dim3(BN_, OCN), 256, 0, stream>>>(out, PIX2, sum2, sq2);
    k_fin  <<<1, 128, 0, stream>>>(sum2, sq2, g2, b2, 1.f / (BN_ * PIX2), sc2, sh2);
    k_bnrelu<<<dim3(50176), 256, 0, stream>>>(out, sc2, sh2);
}

// Round 3
// 566.897 us; speedup vs baseline: 4.3564x; 2.4863x over previous
//
#include <hip/hip_runtime.h>
#include <hip/hip_bf16.h>
#include <cstdint>

// ---------------------------------------------------------------------------
#define IMGSZ 224
#define OUTSZ 112
#define POOLSZ 56
#define OCN 128
#define BN_ 32
#define PIX1 (OUTSZ*OUTSZ)     // 12544
#define PIX2 (POOLSZ*POOLSZ)   // 3136
#define HP 58                  // padded pooled dim (56 + 2)
#define HSTRIDE (HP*HP*OCN)    // elems per n in h2p
#define K1P 168                // LDS K stride (pad 160+8): 84 words, b128-conflict-free
#define K1W 160                // weight K stride (5 chunks of 32)

typedef float f32x4 __attribute__((ext_vector_type(4)));
typedef short bf16x8 __attribute__((ext_vector_type(8)));

__device__ inline short f2bf(float v) {
    __hip_bfloat16 h = __float2bfloat16(v);
    return *(short*)&h;
}
__device__ inline unsigned pack2bf(float a, float b) {
    return (unsigned short)f2bf(a) | ((unsigned)(unsigned short)f2bf(b) << 16);
}

// ---------------------------------------------------------------------------
// Map kernel: per stage-1 output pixel -> 7x7 window origin (padded coords).
__global__ __launch_bounds__(256) void k_map(int2* __restrict__ map) {
    int p = blockIdx.x * 256 + threadIdx.x;
    int oy = p / OUTSZ, ox = p % OUTSZ;
    int e = min(min(oy, ox), min(111 - oy, 111 - ox));
    int s = e >> 3;
    int a = 16 * s, b = a + 16, c = 224 - b, d = 224 - a;
    int ao = a >> 1, bo = b >> 1, co = c >> 1, dd = d >> 1;
    int ti, li, bi, ri;
    if      (oy >= ao && oy < bo && ox >= ao && ox < co) { ti=a; li=a; bi=b; ri=c; }
    else if (oy >= bo && oy < dd && ox >= ao && ox < bo) { ti=b; li=a; bi=d; ri=b; }
    else if (oy >= co && oy < dd && ox >= bo && ox < dd) { ti=c; li=b; bi=d; ri=d; }
    else                                                 { ti=a; li=c; bi=c; ri=d; }
    float scale = (float)(2.0 - (double)s * 0.16666666666666666);
    int tip = (int)((float)(ti + 6) / scale) - 3;
    int lip = (int)((float)(li + 6) / scale) - 3;
    int bip = (int)((float)(bi + 6) / scale) + 3;
    int rip = (int)((float)(ri + 6) / scale) + 3;
    int fh = (bip - tip - 7) / 2 + 1;
    int fw = (rip - lip - 7) / 2 + 1;
    int to = ti >> 1, lo = li >> 1, bo2 = bi >> 1, ro = ri >> 1;
    int i = oy - to, j = ox - lo;
    int pp = (i * fh) / (bo2 - to);
    int qq = (j * fw) / (ro - lo);
    map[p] = make_int2(tip + 2 * pp, lip + 2 * qq);
}

// ---------------------------------------------------------------------------
// Weight packs
__global__ __launch_bounds__(256) void k_wpack1(const float* __restrict__ w1,
                                                short* __restrict__ w1b) {
    int idx = blockIdx.x * 256 + threadIdx.x;   // 80*256 = 20480 = 128*160
    int oc = idx / K1W, k = idx % K1W;
    float v = (k < 147) ? w1[oc * 147 + k] : 0.f;
    w1b[idx] = f2bf(v);
}

__global__ __launch_bounds__(256) void k_wconv(const float* __restrict__ w2,
                                               short* __restrict__ w2b) {
    int idx = blockIdx.x * 256 + threadIdx.x;   // 576*256 = 147456
    int s = idx % 9;
    int t = idx / 9;
    int ic = t & 127;
    int oc = t >> 7;
    w2b[(s * OCN + oc) * OCN + ic] = f2bf(w2[idx]);
}

// ---------------------------------------------------------------------------
// conv1 via MFMA. Block: 128 px (98*128 = 12544 exact), 256 thr.
// Phase 1: gather 147-tap patches -> LDS P[128][168] bf16 (k>=147 zero).
// Phase 2: wave = 128 oc x 32 px, 5 K-chunks of 32, A = w1b from global (L2).
template<int O0, int O1>
__device__ inline void gather_range(const float* __restrict__ ib, int sy, int sx,
                                    short* __restrict__ prow) {
#pragma unroll
    for (int o = O0; o < O1; o++) {
        bf16x8 hv;
#pragma unroll
        for (int e = 0; e < 8; e++) {
            int k = o * 8 + e;
            float v = 0.f;
            if (k < 147) {
                int ic = k / 49, r = k - ic * 49, ky = r / 7, kx = r - ky * 7;
                int y = sy + ky - 3, x = sx + kx - 3;
                if ((unsigned)y < 224u && (unsigned)x < 224u)
                    v = ib[ic * 50176 + y * 224 + x];
            }
            hv[e] = f2bf(v);
        }
        *(bf16x8*)(prow + o * 8) = hv;
    }
}

__global__ __launch_bounds__(256) void k_conv1m(const float* __restrict__ inp,
                                                const short* __restrict__ w1b,
                                                const int2* __restrict__ map,
                                                short* __restrict__ out1b) {
    __shared__ short P[128 * K1P];   // 43008 B
    int tid = threadIdx.x;
    int lpx = tid & 127, part = tid >> 7;     // part is wave-uniform
    int n = blockIdx.y;
    int px_base = blockIdx.x * 128;
    int gpx = px_base + lpx;
    int2 m = map[gpx];
    int sy = m.x, sx = m.y;
    const float* ib = inp + (size_t)n * 3 * 50176;
    short* prow = P + lpx * K1P;
    if (part == 0) gather_range<0, 11>(ib, sy, sx, prow);
    else           gather_range<11, 21>(ib, sy, sx, prow);
    __syncthreads();

    int wave = tid >> 6, lane = tid & 63;
    int q = lane >> 4, l16 = lane & 15;
    f32x4 acc[8][2];
#pragma unroll
    for (int t = 0; t < 8; t++) { acc[t][0] = (f32x4){0,0,0,0}; acc[t][1] = (f32x4){0,0,0,0}; }
    const short* pb0 = P + (wave * 32 + l16) * K1P;
    const short* pb1 = pb0 + 16 * K1P;
#pragma unroll
    for (int icc = 0; icc < 5; icc++) {
        int kof = icc * 32 + q * 8;
        bf16x8 bf0 = *(const bf16x8*)(pb0 + kof);
        bf16x8 bf1 = *(const bf16x8*)(pb1 + kof);
        const short* wb = w1b + l16 * K1W + kof;
#pragma unroll
        for (int t = 0; t < 8; t++) {
            bf16x8 af = *(const bf16x8*)(wb + t * 16 * K1W);
            acc[t][0] = __builtin_amdgcn_mfma_f32_16x16x32_bf16(af, bf0, acc[t][0], 0, 0, 0);
            acc[t][1] = __builtin_amdgcn_mfma_f32_16x16x32_bf16(af, bf1, acc[t][1], 0, 0, 0);
        }
    }
    // C layout: col(px)=l16, row(oc)=q*4+r. Store NHWC bf16, 4 oc packed per 8 B.
    short* ob = out1b + ((size_t)(n * PIX1 + px_base + wave * 32 + l16)) * OCN + q * 4;
#pragma unroll
    for (int t = 0; t < 8; t++) {
#pragma unroll
        for (int g = 0; g < 2; g++) {
            f32x4 a = acc[t][g];
            uint2 u;
            u.x = pack2bf(a[0], a[1]);
            u.y = pack2bf(a[2], a[3]);
            *(uint2*)(ob + (size_t)g * 16 * OCN + t * 16) = u;
        }
    }
}

// ---------------------------------------------------------------------------
// NHWC bf16 per-channel stats; thread = 2 channels, block = 512 px.
__global__ __launch_bounds__(256) void k_statsN(const unsigned* __restrict__ x,
                                                float* __restrict__ sum, float* __restrict__ sumsq) {
    int tid = threadIdx.x;
    int c2 = tid & 63, po = tid >> 6;
    size_t base = (size_t)blockIdx.x * 512;
    const unsigned* xp = x + (base + po) * 64 + c2;
    float s0 = 0, s1 = 0, q0 = 0, q1 = 0;
    for (int i = 0; i < 128; i++) {
        unsigned u = xp[(size_t)i * 256];
        float v0 = __uint_as_float(u << 16);
        float v1 = __uint_as_float(u & 0xffff0000u);
        s0 += v0; q0 += v0 * v0; s1 += v1; q1 += v1 * v1;
    }
    __shared__ float sm[256][4];
    sm[tid][0] = s0; sm[tid][1] = s1; sm[tid][2] = q0; sm[tid][3] = q1;
    __syncthreads();
    if (tid < 64) {
        float a0 = 0, a1 = 0, b0 = 0, b1 = 0;
        for (int w = 0; w < 4; w++) {
            a0 += sm[w * 64 + tid][0]; a1 += sm[w * 64 + tid][1];
            b0 += sm[w * 64 + tid][2]; b1 += sm[w * 64 + tid][3];
        }
        atomicAdd(&sum[2 * tid], a0);   atomicAdd(&sum[2 * tid + 1], a1);
        atomicAdd(&sumsq[2 * tid], b0); atomicAdd(&sumsq[2 * tid + 1], b1);
    }
}

// NCHW per-channel stats (BN2 on d_out).
__global__ __launch_bounds__(256) void k_stats(const float* __restrict__ x, int planeHW,
                                               float* __restrict__ sum, float* __restrict__ sumsq) {
    int n = blockIdx.x, c = blockIdx.y;
    const float* pl = x + ((size_t)(n * OCN + c)) * planeHW;
    float s = 0.f, s2 = 0.f;
    for (int i = threadIdx.x; i < planeHW; i += 256) {
        float v = pl[i];
        s += v; s2 += v * v;
    }
#pragma unroll
    for (int off = 32; off > 0; off >>= 1) {
        s  += __shfl_down(s, off, 64);
        s2 += __shfl_down(s2, off, 64);
    }
    __shared__ float ls[4], ls2[4];
    int wid = threadIdx.x >> 6, lid = threadIdx.x & 63;
    if (lid == 0) { ls[wid] = s; ls2[wid] = s2; }
    __syncthreads();
    if (threadIdx.x == 0) {
        atomicAdd(&sum[c],   ls[0] + ls[1] + ls[2] + ls[3]);
        atomicAdd(&sumsq[c], ls2[0] + ls2[1] + ls2[2] + ls2[3]);
    }
}

__global__ void k_fin(const float* __restrict__ sum, const float* __restrict__ sumsq,
                      const float* __restrict__ gamma, const float* __restrict__ beta,
                      float invN, float* __restrict__ scale, float* __restrict__ shift) {
    int c = threadIdx.x;
    if (c >= OCN) return;
    float m = sum[c] * invN;
    float v = sumsq[c] * invN - m * m;
    float sc = gamma[c] * rsqrtf(v + 1e-5f);
    scale[c] = sc;
    shift[c] = beta[c] - m * sc;
}

// ---------------------------------------------------------------------------
// BN1 affine + 3x3/2 maxpool + ReLU: NHWC bf16 (112x112) -> padded NHWC bf16 (58x58)
// thread = 2 channels (uint), 4 pooled px per block.
__global__ __launch_bounds__(256) void k_bnpool(const unsigned* __restrict__ out1b,
                                                const float* __restrict__ scale,
                                                const float* __restrict__ shift,
                                                unsigned* __restrict__ h2p) {
    int tid = threadIdx.x;
    int c2 = tid & 63, po = tid >> 6;
    int pp = blockIdx.x * 4 + po;
    int n = blockIdx.y;
    int py = pp / POOLSZ, px = pp % POOLSZ;
    const unsigned* base = out1b + (size_t)n * PIX1 * 64;
    float sc0 = scale[2 * c2],     sh0 = shift[2 * c2];
    float sc1 = scale[2 * c2 + 1], sh1 = shift[2 * c2 + 1];
    float m0 = -1e30f, m1 = -1e30f;
#pragma unroll
    for (int dy = 0; dy < 3; dy++) {
        int y = 2 * py - 1 + dy;
        if ((unsigned)y >= (unsigned)OUTSZ) continue;
#pragma unroll
        for (int dx = 0; dx < 3; dx++) {
            int x = 2 * px - 1 + dx;
            if ((unsigned)x >= (unsigned)OUTSZ) continue;
            unsigned u = base[(size_t)(y * OUTSZ + x) * 64 + c2];
            float v0 = __uint_as_float(u << 16);
            float v1 = __uint_as_float(u & 0xffff0000u);
            m0 = fmaxf(m0, fmaf(sc0, v0, sh0));
            m1 = fmaxf(m1, fmaf(sc1, v1, sh1));
        }
    }
    m0 = fmaxf(m0, 0.f); m1 = fmaxf(m1, 0.f);
    h2p[(size_t)n * (HSTRIDE / 2) + ((py + 1) * HP + (px + 1)) * 64 + c2] = pack2bf(m0, m1);
}

// ---------------------------------------------------------------------------
// conv2 via bf16 MFMA: 9 shifted K=128 GEMMs (unchanged from R2).
__global__ __launch_bounds__(256) void k_conv2m(const short* __restrict__ h2p,
                                                const short* __restrict__ w2b,
                                                float* __restrict__ out) {
    int tid = threadIdx.x;
    int wave = tid >> 6, lane = tid & 63;
    int q = lane >> 4, l16 = lane & 15;
    int n = blockIdx.y;
    int px0 = blockIdx.x * 128 + wave * 32 + l16;
    int px1 = px0 + 16;
    bool st0 = px0 < PIX2, st1 = px1 < PIX2;
    int p0 = st0 ? px0 : (PIX2 - 1);
    int p1 = st1 ? px1 : (PIX2 - 1);
    int y0 = p0 / POOLSZ, x0 = p0 % POOLSZ;
    int y1 = p1 / POOLSZ, x1 = p1 % POOLSZ;
    const short* hb = h2p + (size_t)n * HSTRIDE;
    int b0 = (y0 * HP + x0) * OCN;
    int b1 = (y1 * HP + x1) * OCN;

    f32x4 acc[8][2];
#pragma unroll
    for (int t = 0; t < 8; t++) { acc[t][0] = (f32x4){0,0,0,0}; acc[t][1] = (f32x4){0,0,0,0}; }

    for (int icc = 0; icc < 4; icc++) {
        int kof = icc * 32 + q * 8;
#pragma unroll
        for (int s = 0; s < 9; s++) {
            int off = ((s / 3) * HP + (s % 3)) * OCN + kof;
            bf16x8 bf0 = *(const bf16x8*)(hb + b0 + off);
            bf16x8 bf1 = *(const bf16x8*)(hb + b1 + off);
            const short* wbase = w2b + (s * OCN + l16) * OCN + kof;
#pragma unroll
            for (int t = 0; t < 8; t++) {
                bf16x8 af = *(const bf16x8*)(wbase + t * 16 * OCN);
                acc[t][0] = __builtin_amdgcn_mfma_f32_16x16x32_bf16(af, bf0, acc[t][0], 0, 0, 0);
                acc[t][1] = __builtin_amdgcn_mfma_f32_16x16x32_bf16(af, bf1, acc[t][1], 0, 0, 0);
            }
        }
    }
    float* on = out + (size_t)n * OCN * PIX2;
#pragma unroll
    for (int t = 0; t < 8; t++) {
        int ocb = t * 16 + q * 4;
#pragma unroll
        for (int r = 0; r < 4; r++) {
            if (st0) on[(size_t)(ocb + r) * PIX2 + px0] = acc[t][0][r];
            if (st1) on[(size_t)(ocb + r) * PIX2 + px1] = acc[t][1][r];
        }
    }
}

// BN2 affine + ReLU in-place on d_out (NCHW).
__global__ __launch_bounds__(256) void k_bnrelu(float* __restrict__ y,
                                                const float* __restrict__ scale,
                                                const float* __restrict__ shift) {
    size_t i = (size_t)blockIdx.x * 256 + threadIdx.x;
    int c = (int)((i / PIX2) & (OCN - 1));
    float v = fmaf(scale[c], y[i], shift[c]);
    y[i] = fmaxf(v, 0.f);
}

// ---------------------------------------------------------------------------
extern "C" void kernel_launch(void* const* d_in, const int* in_sizes, int n_in,
                              void* d_out, int out_size, void* d_ws, size_t ws_size,
                              hipStream_t stream) {
    const float* inp = (const float*)d_in[0];
    const float* w1  = (const float*)d_in[1];
    const float* g1  = (const float*)d_in[2];
    const float* b1  = (const float*)d_in[3];
    const float* w2  = (const float*)d_in[4];
    const float* g2  = (const float*)d_in[5];
    const float* b2  = (const float*)d_in[6];
    float* out = (float*)d_out;

    char* ws = (char*)d_ws;
    int2*  map   = (int2*)ws;                         // 100,352 B
    float* stats = (float*)(ws + 102400);             // 4 KB
    short* w2b   = (short*)(ws + 106496);             // 294,912 B -> end 401,408
    short* w1b   = (short*)(ws + 401408);             // 40,960 B  -> end 442,368
    short* h2p   = (short*)(ws + 442368);             // 27,557,888 B -> end 28,000,256
    short* out1b = (short*)(ws + 28000256ULL);        // 102,760,448 B -> end 130,760,704

    float* sum1 = stats + 0,   *sq1 = stats + 128, *sc1 = stats + 256, *sh1 = stats + 384;
    float* sum2 = stats + 512, *sq2 = stats + 640, *sc2 = stats + 768, *sh2 = stats + 896;

    hipMemsetAsync(stats, 0, 1024 * sizeof(float), stream);
    hipMemsetAsync(h2p, 0, 27557888ULL, stream);      // zero padding ring

    k_map   <<<dim3(49), 256, 0, stream>>>(map);
    k_wconv <<<dim3(576), 256, 0, stream>>>(w2, w2b);
    k_wpack1<<<dim3(80), 256, 0, stream>>>(w1, w1b);
    k_conv1m<<<dim3(98, BN_), 256, 0, stream>>>(inp, w1b, map, out1b);
    k_statsN<<<dim3(784), 256, 0, stream>>>((const unsigned*)out1b, sum1, sq1);
    k_fin   <<<1, 128, 0, stream>>>(sum1, sq1, g1, b1, 1.f / (BN_ * PIX1), sc1, sh1);
    k_bnpool<<<dim3(PIX2 / 4, BN_), 256, 0, stream>>>((const unsigned*)out1b, sc1, sh1, (unsigned*)h2p);
    k_conv2m<<<dim3(25, BN_), 256, 0, stream>>>(h2p, w2b, out);
    k_stats <<<dim3(BN_, OCN), 256, 0, stream>>>(out, PIX2, sum2, sq2);
    k_fin   <<<1, 128, 0, stream>>>(sum2, sq2, g2, b2, 1.f / (BN_ * PIX2), sc2, sh2);
    k_bnrelu<<<dim3(50176), 256, 0, stream>>>(out, sc2, sh2);
}

// Round 4
// 487.638 us; speedup vs baseline: 5.0644x; 1.1625x over previous
//
#include <hip/hip_runtime.h>
#include <hip/hip_bf16.h>
#include <cstdint>

// ---------------------------------------------------------------------------
#define IMGSZ 224
#define OUTSZ 112
#define POOLSZ 56
#define OCN 128
#define BN_ 32
#define PIX1 (OUTSZ*OUTSZ)     // 12544
#define PIX2 (POOLSZ*POOLSZ)   // 3136
#define HP 58                  // padded pooled dim (56 + 2)
#define HSTRIDE (HP*HP*OCN)    // elems per n in h2p
#define K1P 168                // LDS K stride (pad 160+8): 84 words, b128-conflict-free
#define K1W 160                // weight K stride (5 chunks of 32)

typedef float f32x4 __attribute__((ext_vector_type(4)));
typedef short bf16x8 __attribute__((ext_vector_type(8)));

__device__ inline short f2bf(float v) {
    __hip_bfloat16 h = __float2bfloat16(v);
    return *(short*)&h;
}
__device__ inline unsigned pack2bf(float a, float b) {
    return (unsigned short)f2bf(a) | ((unsigned)(unsigned short)f2bf(b) << 16);
}

// ---------------------------------------------------------------------------
// Map kernel: per stage-1 output pixel -> 7x7 window origin (padded coords).
__global__ __launch_bounds__(256) void k_map(int2* __restrict__ map) {
    int p = blockIdx.x * 256 + threadIdx.x;
    int oy = p / OUTSZ, ox = p % OUTSZ;
    int e = min(min(oy, ox), min(111 - oy, 111 - ox));
    int s = e >> 3;
    int a = 16 * s, b = a + 16, c = 224 - b, d = 224 - a;
    int ao = a >> 1, bo = b >> 1, co = c >> 1, dd = d >> 1;
    int ti, li, bi, ri;
    if      (oy >= ao && oy < bo && ox >= ao && ox < co) { ti=a; li=a; bi=b; ri=c; }
    else if (oy >= bo && oy < dd && ox >= ao && ox < bo) { ti=b; li=a; bi=d; ri=b; }
    else if (oy >= co && oy < dd && ox >= bo && ox < dd) { ti=c; li=b; bi=d; ri=d; }
    else                                                 { ti=a; li=c; bi=c; ri=d; }
    float scale = (float)(2.0 - (double)s * 0.16666666666666666);
    int tip = (int)((float)(ti + 6) / scale) - 3;
    int lip = (int)((float)(li + 6) / scale) - 3;
    int bip = (int)((float)(bi + 6) / scale) + 3;
    int rip = (int)((float)(ri + 6) / scale) + 3;
    int fh = (bip - tip - 7) / 2 + 1;
    int fw = (rip - lip - 7) / 2 + 1;
    int to = ti >> 1, lo = li >> 1, bo2 = bi >> 1, ro = ri >> 1;
    int i = oy - to, j = ox - lo;
    int pp = (i * fh) / (bo2 - to);
    int qq = (j * fw) / (ro - lo);
    map[p] = make_int2(tip + 2 * pp, lip + 2 * qq);
}

// ---------------------------------------------------------------------------
// Weight packs
__global__ __launch_bounds__(256) void k_wpack1(const float* __restrict__ w1,
                                                short* __restrict__ w1b) {
    int idx = blockIdx.x * 256 + threadIdx.x;   // 80*256 = 20480 = 128*160
    int oc = idx / K1W, k = idx % K1W;
    float v = (k < 147) ? w1[oc * 147 + k] : 0.f;
    w1b[idx] = f2bf(v);
}

__global__ __launch_bounds__(256) void k_wconv(const float* __restrict__ w2,
                                               short* __restrict__ w2b) {
    int idx = blockIdx.x * 256 + threadIdx.x;   // 576*256 = 147456
    int s = idx % 9;
    int t = idx / 9;
    int ic = t & 127;
    int oc = t >> 7;
    w2b[(s * OCN + oc) * OCN + ic] = f2bf(w2[idx]);
}

// ---------------------------------------------------------------------------
// conv1 via MFMA. Block: 128 px (98*128 = 12544 exact), 256 thr.
template<int O0, int O1>
__device__ inline void gather_range(const float* __restrict__ ib, int sy, int sx,
                                    short* __restrict__ prow) {
#pragma unroll
    for (int o = O0; o < O1; o++) {
        bf16x8 hv;
#pragma unroll
        for (int e = 0; e < 8; e++) {
            int k = o * 8 + e;
            float v = 0.f;
            if (k < 147) {
                int ic = k / 49, r = k - ic * 49, ky = r / 7, kx = r - ky * 7;
                int y = sy + ky - 3, x = sx + kx - 3;
                if ((unsigned)y < 224u && (unsigned)x < 224u)
                    v = ib[ic * 50176 + y * 224 + x];
            }
            hv[e] = f2bf(v);
        }
        *(bf16x8*)(prow + o * 8) = hv;
    }
}

__global__ __launch_bounds__(256) void k_conv1m(const float* __restrict__ inp,
                                                const short* __restrict__ w1b,
                                                const int2* __restrict__ map,
                                                short* __restrict__ out1b) {
    __shared__ short P[128 * K1P];   // 43008 B
    int tid = threadIdx.x;
    int lpx = tid & 127, part = tid >> 7;
    int n = blockIdx.y;
    int px_base = blockIdx.x * 128;
    int gpx = px_base + lpx;
    int2 m = map[gpx];
    int sy = m.x, sx = m.y;
    const float* ib = inp + (size_t)n * 3 * 50176;
    short* prow = P + lpx * K1P;
    if (part == 0) gather_range<0, 11>(ib, sy, sx, prow);
    else           gather_range<11, 21>(ib, sy, sx, prow);
    __syncthreads();

    int wave = tid >> 6, lane = tid & 63;
    int q = lane >> 4, l16 = lane & 15;
    f32x4 acc[8][2];
#pragma unroll
    for (int t = 0; t < 8; t++) { acc[t][0] = (f32x4){0,0,0,0}; acc[t][1] = (f32x4){0,0,0,0}; }
    const short* pb0 = P + (wave * 32 + l16) * K1P;
    const short* pb1 = pb0 + 16 * K1P;
#pragma unroll
    for (int icc = 0; icc < 5; icc++) {
        int kof = icc * 32 + q * 8;
        bf16x8 bf0 = *(const bf16x8*)(pb0 + kof);
        bf16x8 bf1 = *(const bf16x8*)(pb1 + kof);
        const short* wb = w1b + l16 * K1W + kof;
#pragma unroll
        for (int t = 0; t < 8; t++) {
            bf16x8 af = *(const bf16x8*)(wb + t * 16 * K1W);
            acc[t][0] = __builtin_amdgcn_mfma_f32_16x16x32_bf16(af, bf0, acc[t][0], 0, 0, 0);
            acc[t][1] = __builtin_amdgcn_mfma_f32_16x16x32_bf16(af, bf1, acc[t][1], 0, 0, 0);
        }
    }
    short* ob = out1b + ((size_t)(n * PIX1 + px_base + wave * 32 + l16)) * OCN + q * 4;
#pragma unroll
    for (int t = 0; t < 8; t++) {
#pragma unroll
        for (int g = 0; g < 2; g++) {
            f32x4 a = acc[t][g];
            uint2 u;
            u.x = pack2bf(a[0], a[1]);
            u.y = pack2bf(a[2], a[3]);
            *(uint2*)(ob + (size_t)g * 16 * OCN + t * 16) = u;
        }
    }
}

// ---------------------------------------------------------------------------
// NHWC bf16 per-channel stats; thread = 2 channels, block = 512 px.
__global__ __launch_bounds__(256) void k_statsN(const unsigned* __restrict__ x,
                                                float* __restrict__ sum, float* __restrict__ sumsq) {
    int tid = threadIdx.x;
    int c2 = tid & 63, po = tid >> 6;
    size_t base = (size_t)blockIdx.x * 512;
    const unsigned* xp = x + (base + po) * 64 + c2;
    float s0 = 0, s1 = 0, q0 = 0, q1 = 0;
    for (int i = 0; i < 128; i++) {
        unsigned u = xp[(size_t)i * 256];
        float v0 = __uint_as_float(u << 16);
        float v1 = __uint_as_float(u & 0xffff0000u);
        s0 += v0; q0 += v0 * v0; s1 += v1; q1 += v1 * v1;
    }
    __shared__ float sm[256][4];
    sm[tid][0] = s0; sm[tid][1] = s1; sm[tid][2] = q0; sm[tid][3] = q1;
    __syncthreads();
    if (tid < 64) {
        float a0 = 0, a1 = 0, b0 = 0, b1 = 0;
        for (int w = 0; w < 4; w++) {
            a0 += sm[w * 64 + tid][0]; a1 += sm[w * 64 + tid][1];
            b0 += sm[w * 64 + tid][2]; b1 += sm[w * 64 + tid][3];
        }
        atomicAdd(&sum[2 * tid], a0);   atomicAdd(&sum[2 * tid + 1], a1);
        atomicAdd(&sumsq[2 * tid], b0); atomicAdd(&sumsq[2 * tid + 1], b1);
    }
}

// NCHW per-channel stats (BN2 on d_out).
__global__ __launch_bounds__(256) void k_stats(const float* __restrict__ x, int planeHW,
                                               float* __restrict__ sum, float* __restrict__ sumsq) {
    int n = blockIdx.x, c = blockIdx.y;
    const float* pl = x + ((size_t)(n * OCN + c)) * planeHW;
    float s = 0.f, s2 = 0.f;
    for (int i = threadIdx.x; i < planeHW; i += 256) {
        float v = pl[i];
        s += v; s2 += v * v;
    }
#pragma unroll
    for (int off = 32; off > 0; off >>= 1) {
        s  += __shfl_down(s, off, 64);
        s2 += __shfl_down(s2, off, 64);
    }
    __shared__ float ls[4], ls2[4];
    int wid = threadIdx.x >> 6, lid = threadIdx.x & 63;
    if (lid == 0) { ls[wid] = s; ls2[wid] = s2; }
    __syncthreads();
    if (threadIdx.x == 0) {
        atomicAdd(&sum[c],   ls[0] + ls[1] + ls[2] + ls[3]);
        atomicAdd(&sumsq[c], ls2[0] + ls2[1] + ls2[2] + ls2[3]);
    }
}

__global__ void k_fin(const float* __restrict__ sum, const float* __restrict__ sumsq,
                      const float* __restrict__ gamma, const float* __restrict__ beta,
                      float invN, float* __restrict__ scale, float* __restrict__ shift) {
    int c = threadIdx.x;
    if (c >= OCN) return;
    float m = sum[c] * invN;
    float v = sumsq[c] * invN - m * m;
    float sc = gamma[c] * rsqrtf(v + 1e-5f);
    scale[c] = sc;
    shift[c] = beta[c] - m * sc;
}

// ---------------------------------------------------------------------------
// BN1 affine + 3x3/2 maxpool + ReLU: NHWC bf16 (112x112) -> padded NHWC bf16 (58x58)
__global__ __launch_bounds__(256) void k_bnpool(const unsigned* __restrict__ out1b,
                                                const float* __restrict__ scale,
                                                const float* __restrict__ shift,
                                                unsigned* __restrict__ h2p) {
    int tid = threadIdx.x;
    int c2 = tid & 63, po = tid >> 6;
    int pp = blockIdx.x * 4 + po;
    int n = blockIdx.y;
    int py = pp / POOLSZ, px = pp % POOLSZ;
    const unsigned* base = out1b + (size_t)n * PIX1 * 64;
    float sc0 = scale[2 * c2],     sh0 = shift[2 * c2];
    float sc1 = scale[2 * c2 + 1], sh1 = shift[2 * c2 + 1];
    float m0 = -1e30f, m1 = -1e30f;
#pragma unroll
    for (int dy = 0; dy < 3; dy++) {
        int y = 2 * py - 1 + dy;
        if ((unsigned)y >= (unsigned)OUTSZ) continue;
#pragma unroll
        for (int dx = 0; dx < 3; dx++) {
            int x = 2 * px - 1 + dx;
            if ((unsigned)x >= (unsigned)OUTSZ) continue;
            unsigned u = base[(size_t)(y * OUTSZ + x) * 64 + c2];
            float v0 = __uint_as_float(u << 16);
            float v1 = __uint_as_float(u & 0xffff0000u);
            m0 = fmaxf(m0, fmaf(sc0, v0, sh0));
            m1 = fmaxf(m1, fmaf(sc1, v1, sh1));
        }
    }
    m0 = fmaxf(m0, 0.f); m1 = fmaxf(m1, 0.f);
    h2p[(size_t)n * (HSTRIDE / 2) + ((py + 1) * HP + (px + 1)) * 64 + c2] = pack2bf(m0, m1);
}

// ---------------------------------------------------------------------------
// conv2 via bf16 MFMA: 9 shifted K=128 GEMMs.
// R4: wave = 128 oc x 64 px (acc 8x4), __launch_bounds__(256,2) so the
// compiler has a 256-VGPR budget to keep the 12 loads/step in flight.
// Grid: (13, 32) — 13*256 px covers 3136 with tail masked.
__global__ __launch_bounds__(256, 2) void k_conv2m(const short* __restrict__ h2p,
                                                   const short* __restrict__ w2b,
                                                   float* __restrict__ out) {
    int tid = threadIdx.x;
    int wave = tid >> 6, lane = tid & 63;
    int q = lane >> 4, l16 = lane & 15;
    int n = blockIdx.y;
    int pxb = blockIdx.x * 256 + wave * 64 + l16;
    bool st[4];
    int bofs[4];
#pragma unroll
    for (int g = 0; g < 4; g++) {
        int p = pxb + g * 16;
        st[g] = p < PIX2;
        int pc = st[g] ? p : (PIX2 - 1);
        int y = pc / POOLSZ, x = pc % POOLSZ;
        bofs[g] = (y * HP + x) * OCN;
    }
    const short* hb = h2p + (size_t)n * HSTRIDE;

    f32x4 acc[8][4];
#pragma unroll
    for (int t = 0; t < 8; t++)
#pragma unroll
        for (int g = 0; g < 4; g++) acc[t][g] = (f32x4){0, 0, 0, 0};

    for (int icc = 0; icc < 4; icc++) {
        int kof = icc * 32 + q * 8;
#pragma unroll
        for (int s = 0; s < 9; s++) {
            int off = ((s / 3) * HP + (s % 3)) * OCN + kof;
            bf16x8 bf[4];
#pragma unroll
            for (int g = 0; g < 4; g++) bf[g] = *(const bf16x8*)(hb + bofs[g] + off);
            const short* wbase = w2b + (s * OCN + l16) * OCN + kof;
#pragma unroll
            for (int t = 0; t < 8; t++) {
                bf16x8 af = *(const bf16x8*)(wbase + t * 16 * OCN);
#pragma unroll
                for (int g = 0; g < 4; g++)
                    acc[t][g] = __builtin_amdgcn_mfma_f32_16x16x32_bf16(af, bf[g], acc[t][g], 0, 0, 0);
            }
        }
    }
    // C/D layout: col(px)=l16, row(oc)=q*4+reg
    float* on = out + (size_t)n * OCN * PIX2;
#pragma unroll
    for (int t = 0; t < 8; t++) {
        int ocb = t * 16 + q * 4;
#pragma unroll
        for (int g = 0; g < 4; g++) {
            if (!st[g]) continue;
            int p = pxb + g * 16;
#pragma unroll
            for (int r = 0; r < 4; r++)
                on[(size_t)(ocb + r) * PIX2 + p] = acc[t][g][r];
        }
    }
}

// BN2 affine + ReLU in-place on d_out (NCHW).
__global__ __launch_bounds__(256) void k_bnrelu(float* __restrict__ y,
                                                const float* __restrict__ scale,
                                                const float* __restrict__ shift) {
    size_t i = (size_t)blockIdx.x * 256 + threadIdx.x;
    int c = (int)((i / PIX2) & (OCN - 1));
    float v = fmaf(scale[c], y[i], shift[c]);
    y[i] = fmaxf(v, 0.f);
}

// ---------------------------------------------------------------------------
extern "C" void kernel_launch(void* const* d_in, const int* in_sizes, int n_in,
                              void* d_out, int out_size, void* d_ws, size_t ws_size,
                              hipStream_t stream) {
    const float* inp = (const float*)d_in[0];
    const float* w1  = (const float*)d_in[1];
    const float* g1  = (const float*)d_in[2];
    const float* b1  = (const float*)d_in[3];
    const float* w2  = (const float*)d_in[4];
    const float* g2  = (const float*)d_in[5];
    const float* b2  = (const float*)d_in[6];
    float* out = (float*)d_out;

    char* ws = (char*)d_ws;
    int2*  map   = (int2*)ws;                         // 100,352 B
    float* stats = (float*)(ws + 102400);             // 4 KB
    short* w2b   = (short*)(ws + 106496);             // 294,912 B -> end 401,408
    short* w1b   = (short*)(ws + 401408);             // 40,960 B  -> end 442,368
    short* h2p   = (short*)(ws + 442368);             // 27,557,888 B -> end 28,000,256
    short* out1b = (short*)(ws + 28000256ULL);        // 102,760,448 B -> end 130,760,704

    float* sum1 = stats + 0,   *sq1 = stats + 128, *sc1 = stats + 256, *sh1 = stats + 384;
    float* sum2 = stats + 512, *sq2 = stats + 640, *sc2 = stats + 768, *sh2 = stats + 896;

    hipMemsetAsync(stats, 0, 1024 * sizeof(float), stream);
    hipMemsetAsync(h2p, 0, 27557888ULL, stream);      // zero padding ring

    k_map   <<<dim3(49), 256, 0, stream>>>(map);
    k_wconv <<<dim3(576), 256, 0, stream>>>(w2, w2b);
    k_wpack1<<<dim3(80), 256, 0, stream>>>(w1, w1b);
    k_conv1m<<<dim3(98, BN_), 256, 0, stream>>>(inp, w1b, map, out1b);
    k_statsN<<<dim3(784), 256, 0, stream>>>((const unsigned*)out1b, sum1, sq1);
    k_fin   <<<1, 128, 0, stream>>>(sum1, sq1, g1, b1, 1.f / (BN_ * PIX1), sc1, sh1);
    k_bnpool<<<dim3(PIX2 / 4, BN_), 256, 0, stream>>>((const unsigned*)out1b, sc1, sh1, (unsigned*)h2p);
    k_conv2m<<<dim3(13, BN_), 256, 0, stream>>>(h2p, w2b, out);
    k_stats <<<dim3(BN_, OCN), 256, 0, stream>>>(out, PIX2, sum2, sq2);
    k_fin   <<<1, 128, 0, stream>>>(sum2, sq2, g2, b2, 1.f / (BN_ * PIX2), sc2, sh2);
    k_bnrelu<<<dim3(50176), 256, 0, stream>>>(out, sc2, sh2);
}

// Round 5
// 478.467 us; speedup vs baseline: 5.1615x; 1.0192x over previous
//
#include <hip/hip_runtime.h>
#include <hip/hip_bf16.h>
#include <cstdint>

// ---------------------------------------------------------------------------
#define IMGSZ 224
#define OUTSZ 112
#define POOLSZ 56
#define OCN 128
#define BN_ 32
#define PIX1 (OUTSZ*OUTSZ)     // 12544
#define PIX2 (POOLSZ*POOLSZ)   // 3136
#define HP 58                  // padded pooled dim (56 + 2)
#define HSTRIDE (HP*HP*OCN)    // elems per n in h2p
#define PW 240                 // padded input row stride (x in [-3,236))
#define PH 233                 // padded input rows (y in [-3,230))
#define PPL (PH*PW)            // 55920 floats per padded plane
#define K1C 192                // conv1 K: 24 groups of 8 = (ic*7+ky)*8+kx layout

typedef float f32x4 __attribute__((ext_vector_type(4)));
typedef short bf16x8 __attribute__((ext_vector_type(8)));
struct alignas(4) f4u { float v[4]; };   // 4-byte-aligned 16B load

__device__ inline short f2bf(float v) {
    __hip_bfloat16 h = __float2bfloat16(v);
    return *(short*)&h;
}
__device__ inline unsigned pack2bf(float a, float b) {
    return (unsigned short)f2bf(a) | ((unsigned)(unsigned short)f2bf(b) << 16);
}

// ---------------------------------------------------------------------------
// Map kernel: per stage-1 output pixel -> 7x7 window origin (padded coords, >=0).
__global__ __launch_bounds__(256) void k_map(int2* __restrict__ map) {
    int p = blockIdx.x * 256 + threadIdx.x;
    int oy = p / OUTSZ, ox = p % OUTSZ;
    int e = min(min(oy, ox), min(111 - oy, 111 - ox));
    int s = e >> 3;
    int a = 16 * s, b = a + 16, c = 224 - b, d = 224 - a;
    int ao = a >> 1, bo = b >> 1, co = c >> 1, dd = d >> 1;
    int ti, li, bi, ri;
    if      (oy >= ao && oy < bo && ox >= ao && ox < co) { ti=a; li=a; bi=b; ri=c; }
    else if (oy >= bo && oy < dd && ox >= ao && ox < bo) { ti=b; li=a; bi=d; ri=b; }
    else if (oy >= co && oy < dd && ox >= bo && ox < dd) { ti=c; li=b; bi=d; ri=d; }
    else                                                 { ti=a; li=c; bi=c; ri=d; }
    float scale = (float)(2.0 - (double)s * 0.16666666666666666);
    int tip = (int)((float)(ti + 6) / scale) - 3;
    int lip = (int)((float)(li + 6) / scale) - 3;
    int bip = (int)((float)(bi + 6) / scale) + 3;
    int rip = (int)((float)(ri + 6) / scale) + 3;
    int fh = (bip - tip - 7) / 2 + 1;
    int fw = (rip - lip - 7) / 2 + 1;
    int to = ti >> 1, lo = li >> 1, bo2 = bi >> 1, ro = ri >> 1;
    int i = oy - to, j = ox - lo;
    int pp = (i * fh) / (bo2 - to);
    int qq = (j * fw) / (ro - lo);
    map[p] = make_int2(tip + 2 * pp, lip + 2 * qq);
}

// ---------------------------------------------------------------------------
// Zero-haloed padded input: pad[pl][y][x] = img[pl][y-3][x-3] or 0.
__global__ __launch_bounds__(256) void k_pad(const float* __restrict__ inp,
                                             float* __restrict__ pad) {
    int x = threadIdx.x;
    if (x >= PW) return;
    int y = blockIdx.x;       // 0..232
    int pl = blockIdx.y;      // 0..95
    int iy = y - 3, ix = x - 3;
    float v = ((unsigned)iy < 224u && (unsigned)ix < 224u)
                ? inp[(size_t)pl * 50176 + iy * 224 + ix] : 0.f;
    pad[(size_t)pl * PPL + y * PW + x] = v;
}

// ---------------------------------------------------------------------------
// Weight packs. w1b: [oc][k'] with k' = (ic*7+ky)*8 + kx (kx<7), zero-padded to 192.
__global__ __launch_bounds__(256) void k_wpack1(const float* __restrict__ w1,
                                                short* __restrict__ w1b) {
    int idx = blockIdx.x * 256 + threadIdx.x;   // 96*256 = 24576 = 128*192
    int oc = idx / K1C, k = idx % K1C;
    int g8 = k >> 3, e = k & 7;
    float v = 0.f;
    if (g8 < 21 && e < 7) {
        int ic = g8 / 7, ky = g8 - ic * 7;
        v = w1[((oc * 3 + ic) * 7 + ky) * 7 + e];
    }
    w1b[idx] = f2bf(v);
}

__global__ __launch_bounds__(256) void k_wconv(const float* __restrict__ w2,
                                               short* __restrict__ w2b) {
    int idx = blockIdx.x * 256 + threadIdx.x;   // 576*256 = 147456
    int s = idx % 9;
    int t = idx / 9;
    int ic = t & 127;
    int oc = t >> 7;
    w2b[(s * OCN + oc) * OCN + ic] = f2bf(w2[idx]);
}

// ---------------------------------------------------------------------------
// conv1 via MFMA. Block = 64 px (196*64 = 12544), 4 waves, LDS 24576 B.
// Gather: thread = pixel lane, (ic,ky)-pairs strided by wave; per pair two
// unconditional dwordx4 loads from the padded image -> one b128 LDS write,
// column XOR-swizzled by (row&7) for conflict-free b128.
// MFMA: wave = 64 oc (half, wave&1) x 32 px (half, wave>>1); 6 K-chunks of 32.
// Epilogue: NHWC bf16 store + fused BN1 sum/sumsq (shuffle-reduce + atomics).
__global__ __launch_bounds__(256) void k_conv1m(const float* __restrict__ pad,
                                                const short* __restrict__ w1b,
                                                const int2* __restrict__ map,
                                                short* __restrict__ out1b,
                                                float* __restrict__ sum1x,
                                                float* __restrict__ sq1x) {
    __shared__ short P[64 * K1C];   // 24576 B
    int tid = threadIdx.x;
    int wave = tid >> 6, lane = tid & 63;
    int n = blockIdx.y;
    int px_base = blockIdx.x * 64;

    {   // gather phase
        int2 m = map[px_base + lane];
        int sy = m.x, sx = m.y;                 // padded-origin coords (>=0)
        const float* pb = pad + (size_t)n * 3 * PPL;
        short* prow = P + lane * K1C;
        int sw = lane & 7;
#pragma unroll
        for (int i = 0; i < 6; i++) {
            int pair = wave + 4 * i;            // wave-uniform
            uint4 u = make_uint4(0, 0, 0, 0);
            if (pair < 21) {
                int ic = pair / 7, ky = pair - ic * 7;
                const float* row = pb + (size_t)ic * PPL + (sy + ky) * PW + sx;
                f4u a = *(const f4u*)row;
                f4u b = *(const f4u*)(row + 4);
                u.x = pack2bf(a.v[0], a.v[1]);
                u.y = pack2bf(a.v[2], a.v[3]);
                u.z = pack2bf(b.v[0], b.v[1]);
                u.w = pack2bf(b.v[2], 0.f);
            }
            *(uint4*)(prow + ((pair ^ sw) << 3)) = u;
        }
    }
    __syncthreads();

    int q = lane >> 4, l16 = lane & 15;
    int ochalf = wave & 1, pxhalf = wave >> 1;
    f32x4 acc[4][2];
#pragma unroll
    for (int t = 0; t < 4; t++) { acc[t][0] = (f32x4){0,0,0,0}; acc[t][1] = (f32x4){0,0,0,0}; }

    int r0 = pxhalf * 32 + l16;
    const short* prow0 = P + r0 * K1C;
    const short* prow1 = prow0 + 16 * K1C;
    int sw = r0 & 7;                            // same for r0 and r0+16
    const short* wb = w1b + (ochalf * 64 + l16) * K1C;
#pragma unroll
    for (int icc = 0; icc < 6; icc++) {
        int lg = icc * 4 + q;
        int pg = ((lg ^ sw) << 3);
        bf16x8 bf0 = *(const bf16x8*)(prow0 + pg);
        bf16x8 bf1 = *(const bf16x8*)(prow1 + pg);
        int kof = icc * 32 + q * 8;
#pragma unroll
        for (int t = 0; t < 4; t++) {
            bf16x8 af = *(const bf16x8*)(wb + t * 16 * K1C + kof);
            acc[t][0] = __builtin_amdgcn_mfma_f32_16x16x32_bf16(af, bf0, acc[t][0], 0, 0, 0);
            acc[t][1] = __builtin_amdgcn_mfma_f32_16x16x32_bf16(af, bf1, acc[t][1], 0, 0, 0);
        }
    }

    // epilogue: C layout col(px)=l16, row(oc)=q*4+r
    short* ob = out1b + ((size_t)(n * PIX1) + px_base + pxhalf * 32 + l16) * OCN
                + ochalf * 64 + q * 4;
#pragma unroll
    for (int t = 0; t < 4; t++) {
#pragma unroll
        for (int g = 0; g < 2; g++) {
            f32x4 a = acc[t][g];
            uint2 u;
            u.x = pack2bf(a[0], a[1]);
            u.y = pack2bf(a[2], a[3]);
            *(uint2*)(ob + g * 16 * OCN + t * 16) = u;
        }
    }

    // fused BN1 stats: sum over this wave's 32 px, per oc; atomics per (n,oc)
    float* s1 = sum1x + n * OCN;
    float* z1 = sq1x + n * OCN;
#pragma unroll
    for (int t = 0; t < 4; t++) {
#pragma unroll
        for (int r = 0; r < 4; r++) {
            float a0 = acc[t][0][r], a1 = acc[t][1][r];
            float s = a0 + a1;
            float z = fmaf(a0, a0, a1 * a1);
#pragma unroll
            for (int msk = 1; msk < 16; msk <<= 1) {
                s += __shfl_xor(s, msk, 64);
                z += __shfl_xor(z, msk, 64);
            }
            if (l16 == 0) {
                int oc = ochalf * 64 + t * 16 + q * 4 + r;
                atomicAdd(&s1[oc], s);
                atomicAdd(&z1[oc], z);
            }
        }
    }
}

// ---------------------------------------------------------------------------
// Finalize BN params from per-n partial sums: 32x128 -> scale/shift.
__global__ void k_fin2(const float* __restrict__ sumx, const float* __restrict__ sqx,
                       const float* __restrict__ gamma, const float* __restrict__ beta,
                       float invN, float* __restrict__ scale, float* __restrict__ shift) {
    int c = threadIdx.x;
    if (c >= OCN) return;
    float s = 0.f, q = 0.f;
    for (int n = 0; n < BN_; n++) { s += sumx[n * OCN + c]; q += sqx[n * OCN + c]; }
    float m = s * invN;
    float v = q * invN - m * m;
    float sc = gamma[c] * rsqrtf(v + 1e-5f);
    scale[c] = sc;
    shift[c] = beta[c] - m * sc;
}

// ---------------------------------------------------------------------------
// BN1 affine + 3x3/2 maxpool + ReLU: NHWC bf16 (112x112) -> padded NHWC bf16 (58x58)
__global__ __launch_bounds__(256) void k_bnpool(const unsigned* __restrict__ out1b,
                                                const float* __restrict__ scale,
                                                const float* __restrict__ shift,
                                                unsigned* __restrict__ h2p) {
    int tid = threadIdx.x;
    int c2 = tid & 63, po = tid >> 6;
    int pp = blockIdx.x * 4 + po;
    int n = blockIdx.y;
    int py = pp / POOLSZ, px = pp % POOLSZ;
    const unsigned* base = out1b + (size_t)n * PIX1 * 64;
    float sc0 = scale[2 * c2],     sh0 = shift[2 * c2];
    float sc1 = scale[2 * c2 + 1], sh1 = shift[2 * c2 + 1];
    float m0 = -1e30f, m1 = -1e30f;
#pragma unroll
    for (int dy = 0; dy < 3; dy++) {
        int y = 2 * py - 1 + dy;
        if ((unsigned)y >= (unsigned)OUTSZ) continue;
#pragma unroll
        for (int dx = 0; dx < 3; dx++) {
            int x = 2 * px - 1 + dx;
            if ((unsigned)x >= (unsigned)OUTSZ) continue;
            unsigned u = base[(size_t)(y * OUTSZ + x) * 64 + c2];
            float v0 = __uint_as_float(u << 16);
            float v1 = __uint_as_float(u & 0xffff0000u);
            m0 = fmaxf(m0, fmaf(sc0, v0, sh0));
            m1 = fmaxf(m1, fmaf(sc1, v1, sh1));
        }
    }
    m0 = fmaxf(m0, 0.f); m1 = fmaxf(m1, 0.f);
    h2p[(size_t)n * (HSTRIDE / 2) + ((py + 1) * HP + (px + 1)) * 64 + c2] = pack2bf(m0, m1);
}

// ---------------------------------------------------------------------------
// conv2 via bf16 MFMA: 9 shifted K=128 GEMMs; wave = 128 oc x 64 px.
// Fused BN2 stats in epilogue.
__global__ __launch_bounds__(256, 2) void k_conv2m(const short* __restrict__ h2p,
                                                   const short* __restrict__ w2b,
                                                   float* __restrict__ out,
                                                   float* __restrict__ sum2x,
                                                   float* __restrict__ sq2x) {
    int tid = threadIdx.x;
    int wave = tid >> 6, lane = tid & 63;
    int q = lane >> 4, l16 = lane & 15;
    int n = blockIdx.y;
    int pxb = blockIdx.x * 256 + wave * 64 + l16;
    bool st[4];
    int bofs[4];
#pragma unroll
    for (int g = 0; g < 4; g++) {
        int p = pxb + g * 16;
        st[g] = p < PIX2;
        int pc = st[g] ? p : (PIX2 - 1);
        int y = pc / POOLSZ, x = pc % POOLSZ;
        bofs[g] = (y * HP + x) * OCN;
    }
    const short* hb = h2p + (size_t)n * HSTRIDE;

    f32x4 acc[8][4];
#pragma unroll
    for (int t = 0; t < 8; t++)
#pragma unroll
        for (int g = 0; g < 4; g++) acc[t][g] = (f32x4){0, 0, 0, 0};

    for (int icc = 0; icc < 4; icc++) {
        int kof = icc * 32 + q * 8;
#pragma unroll
        for (int s = 0; s < 9; s++) {
            int off = ((s / 3) * HP + (s % 3)) * OCN + kof;
            bf16x8 bf[4];
#pragma unroll
            for (int g = 0; g < 4; g++) bf[g] = *(const bf16x8*)(hb + bofs[g] + off);
            const short* wbase = w2b + (s * OCN + l16) * OCN + kof;
#pragma unroll
            for (int t = 0; t < 8; t++) {
                bf16x8 af = *(const bf16x8*)(wbase + t * 16 * OCN);
#pragma unroll
                for (int g = 0; g < 4; g++)
                    acc[t][g] = __builtin_amdgcn_mfma_f32_16x16x32_bf16(af, bf[g], acc[t][g], 0, 0, 0);
            }
        }
    }
    // C/D layout: col(px)=l16, row(oc)=q*4+reg
    float* on = out + (size_t)n * OCN * PIX2;
#pragma unroll
    for (int t = 0; t < 8; t++) {
        int ocb = t * 16 + q * 4;
#pragma unroll
        for (int g = 0; g < 4; g++) {
            if (!st[g]) continue;
            int p = pxb + g * 16;
#pragma unroll
            for (int r = 0; r < 4; r++)
                on[(size_t)(ocb + r) * PIX2 + p] = acc[t][g][r];
        }
    }
    // fused BN2 stats
    if (st[0]) {
        float* s2 = sum2x + n * OCN;
        float* z2 = sq2x + n * OCN;
#pragma unroll
        for (int t = 0; t < 8; t++) {
#pragma unroll
            for (int r = 0; r < 4; r++) {
                float s = 0.f, z = 0.f;
#pragma unroll
                for (int g = 0; g < 4; g++) {
                    if (!st[g]) continue;
                    float v = acc[t][g][r];
                    s += v;
                    z = fmaf(v, v, z);
                }
#pragma unroll
                for (int msk = 1; msk < 16; msk <<= 1) {
                    s += __shfl_xor(s, msk, 64);
                    z += __shfl_xor(z, msk, 64);
                }
                if (l16 == 0) {
                    int oc = t * 16 + q * 4 + r;
                    atomicAdd(&s2[oc], s);
                    atomicAdd(&z2[oc], z);
                }
            }
        }
    }
}

// BN2 affine + ReLU in-place on d_out (NCHW).
__global__ __launch_bounds__(256) void k_bnrelu(float* __restrict__ y,
                                                const float* __restrict__ scale,
                                                const float* __restrict__ shift) {
    size_t i = (size_t)blockIdx.x * 256 + threadIdx.x;
    int c = (int)((i / PIX2) & (OCN - 1));
    float v = fmaf(scale[c], y[i], shift[c]);
    y[i] = fmaxf(v, 0.f);
}

// ---------------------------------------------------------------------------
extern "C" void kernel_launch(void* const* d_in, const int* in_sizes, int n_in,
                              void* d_out, int out_size, void* d_ws, size_t ws_size,
                              hipStream_t stream) {
    const float* inp = (const float*)d_in[0];
    const float* w1  = (const float*)d_in[1];
    const float* g1  = (const float*)d_in[2];
    const float* b1  = (const float*)d_in[3];
    const float* w2  = (const float*)d_in[4];
    const float* g2  = (const float*)d_in[5];
    const float* b2  = (const float*)d_in[6];
    float* out = (float*)d_out;

    char* ws = (char*)d_ws;
    int2*  map   = (int2*)ws;                         // 100,352 B
    float* stats = (float*)(ws + 102400);             // 67,584 B used
    short* w2b   = (short*)(ws + 176128);             // 294,912 B -> 471,040
    short* w1b   = (short*)(ws + 471040);             // 49,152 B  -> 520,192
    float* pad   = (float*)(ws + 520192);             // 21,473,280 B -> 21,993,472
    short* h2p   = (short*)(ws + 21993472ULL);        // 27,557,888 B -> 49,551,360
    short* out1b = (short*)(ws + 49551360ULL);        // 102,760,448 B -> 152,311,808

    float* sum1x = stats;                // 32*128
    float* sq1x  = stats + 4096;
    float* sum2x = stats + 8192;
    float* sq2x  = stats + 12288;
    float* sc1   = stats + 16384, *sh1 = stats + 16512;
    float* sc2   = stats + 16640, *sh2 = stats + 16768;

    hipMemsetAsync(stats, 0, 16384 * sizeof(float), stream);
    hipMemsetAsync(h2p, 0, 27557888ULL, stream);      // zero padding ring

    k_map   <<<dim3(49), 256, 0, stream>>>(map);
    k_wconv <<<dim3(576), 256, 0, stream>>>(w2, w2b);
    k_wpack1<<<dim3(96), 256, 0, stream>>>(w1, w1b);
    k_pad   <<<dim3(PH, 96), 256, 0, stream>>>(inp, pad);
    k_conv1m<<<dim3(196, BN_), 256, 0, stream>>>(pad, w1b, map, out1b, sum1x, sq1x);
    k_fin2  <<<1, 128, 0, stream>>>(sum1x, sq1x, g1, b1, 1.f / (BN_ * PIX1), sc1, sh1);
    k_bnpool<<<dim3(PIX2 / 4, BN_), 256, 0, stream>>>((const unsigned*)out1b, sc1, sh1, (unsigned*)h2p);
    k_conv2m<<<dim3(13, BN_), 256, 0, stream>>>(h2p, w2b, out, sum2x, sq2x);
    k_fin2  <<<1, 128, 0, stream>>>(sum2x, sq2x, g2, b2, 1.f / (BN_ * PIX2), sc2, sh2);
    k_bnrelu<<<dim3(50176), 256, 0, stream>>>(out, sc2, sh2);
}